// Round 2
// baseline (128.082 us; speedup 1.0000x reference)
//
#include <hip/hip_runtime.h>
#include <stdint.h>

#define BN_TOTAL 25600   // B*N = 256*100
#define DDIM 128
#define KN 16

typedef __bf16 bf16x8 __attribute__((ext_vector_type(8)));
typedef float f32x4 __attribute__((ext_vector_type(4)));
typedef float f32x16 __attribute__((ext_vector_type(16)));
typedef unsigned short u16x8 __attribute__((ext_vector_type(8)));

__device__ __forceinline__ unsigned short f2bf(float x) {
    unsigned int u = __builtin_bit_cast(unsigned int, x);
    u = (u + 0x7fffu + ((u >> 16) & 1u)) >> 16;   // RNE
    return (unsigned short)u;
}

// ---------------- Kernel 1: attention + aggregation -> agg[BN][128] ----------
// One wave per (b,n).
// Stage 1: h = leaky(feat @ w1) via mfma_16x16x32 (M=16 nbrs, N=128, K=128),
//          weight column folded into acc init.
// Stage 2: agg = alpha^T @ nbr via mfma_32x32x16 (K=16 nbrs exactly, N=128 in
//          4 tiles of 32) — replaces the 128-shuffle butterfly.
__global__ __launch_bounds__(256) void k1_attn_agg(
    const float* __restrict__ nbr,    // [BN,16,128]
    const float* __restrict__ wgt,    // [BN,16]
    const float* __restrict__ extra,  // [BN,128]
    const float* __restrict__ w1,     // [129,128]
    const float* __restrict__ w2,     // [128]
    float* __restrict__ agg)          // [BN,128]
{
    __shared__ uint4 b1frag[32][64];   // [t*4+s][lane] : w1 B-fragments, 32 KB
    __shared__ float w1last[DDIM];
    __shared__ float w2s[DDIM];

    const int tid  = threadIdx.x;
    const int lane = tid & 63;
    const int wave = tid >> 6;
    const int grp  = lane >> 4;   // 0..3
    const int lr   = lane & 15;   // 0..15
    const int half = lane >> 5;   // 0..1  (for 32x32 MFMA)
    const int col  = lane & 31;   // 0..31 (for 32x32 MFMA)

    // ---- one-time per block: build w1 fragments (wave w fills k-step s=w)
    {
        const int s = wave;
        const int fbase = grp * 8 + 32 * s;
        for (int t = 0; t < 8; ++t) {
            const int d = t * 16 + lr;
            u16x8 tmp;
            #pragma unroll
            for (int j = 0; j < 8; ++j)
                tmp[j] = f2bf(w1[(fbase + j) * DDIM + d]);
            b1frag[t * 4 + s][lane] = __builtin_bit_cast(uint4, tmp);
        }
        if (tid < DDIM) {
            w1last[tid] = w1[DDIM * DDIM + tid];  // row 128 of w1
            w2s[tid]    = w2[tid];
        }
    }
    __syncthreads();

    const int stride = gridDim.x * 4;
    for (int bn = blockIdx.x * 4 + wave; bn < BN_TOTAL; bn += stride) {
        const float* nb = nbr   + (size_t)bn * (KN * DDIM);
        const float* ex = extra + (size_t)bn * DDIM;

        // ---- issue B2 loads first: nbr in 32x32x16 B-fragment layout.
        // lane needs nbr[k = half*8+j][f = t*32+col]; per instr the wave covers
        // 2 rows x 128B contiguous -> these first-touch the whole 8KB tile.
        float b2raw[4][8];
        #pragma unroll
        for (int t = 0; t < 4; ++t)
            #pragma unroll
            for (int j = 0; j < 8; ++j)
                b2raw[t][j] = nb[(half * 8 + j) * DDIM + t * 32 + col];

        // acc init = weight[r] * w1[128][d]   (rows r = grp*4+j, col d = t*16+lr)
        const float4 wv = *(const float4*)(wgt + (size_t)bn * KN + grp * 4);
        f32x4 acc[8];
        #pragma unroll
        for (int t = 0; t < 8; ++t) {
            const float wl = w1last[t * 16 + lr];
            acc[t][0] = wv.x * wl;
            acc[t][1] = wv.y * wl;
            acc[t][2] = wv.z * wl;
            acc[t][3] = wv.w * wl;
        }

        // ---- stage 1: h = feat @ w1  (A-frags from global, B-frags from LDS)
        #pragma unroll
        for (int s = 0; s < 4; ++s) {
            const int f0 = grp * 8 + 32 * s;
            const float4 n0 = *(const float4*)(nb + lr * DDIM + f0);
            const float4 n1 = *(const float4*)(nb + lr * DDIM + f0 + 4);
            const float4 e0 = *(const float4*)(ex + f0);
            const float4 e1 = *(const float4*)(ex + f0 + 4);
            u16x8 au;
            au[0] = f2bf(n0.x * e0.x); au[1] = f2bf(n0.y * e0.y);
            au[2] = f2bf(n0.z * e0.z); au[3] = f2bf(n0.w * e0.w);
            au[4] = f2bf(n1.x * e1.x); au[5] = f2bf(n1.y * e1.y);
            au[6] = f2bf(n1.z * e1.z); au[7] = f2bf(n1.w * e1.w);
            const bf16x8 af = __builtin_bit_cast(bf16x8, au);
            #pragma unroll
            for (int t = 0; t < 8; ++t) {
                const bf16x8 bf = __builtin_bit_cast(bf16x8, b1frag[t * 4 + s][lane]);
                acc[t] = __builtin_amdgcn_mfma_f32_16x16x32_bf16(af, bf, acc[t], 0, 0, 0);
            }
        }

        // ---- leaky_relu(0.2) + dot with w2 -> logits for rows grp*4+r
        float sum0 = 0.f, sum1 = 0.f, sum2 = 0.f, sum3 = 0.f;
        #pragma unroll
        for (int t = 0; t < 8; ++t) {
            const float w2v = w2s[t * 16 + lr];
            float h;
            h = acc[t][0]; h = fmaxf(h, 0.2f * h); sum0 = fmaf(h, w2v, sum0);
            h = acc[t][1]; h = fmaxf(h, 0.2f * h); sum1 = fmaf(h, w2v, sum1);
            h = acc[t][2]; h = fmaxf(h, 0.2f * h); sum2 = fmaf(h, w2v, sum2);
            h = acc[t][3]; h = fmaxf(h, 0.2f * h); sum3 = fmaf(h, w2v, sum3);
        }
        #pragma unroll
        for (int m = 1; m <= 8; m <<= 1) {
            sum0 += __shfl_xor(sum0, m, 64);
            sum1 += __shfl_xor(sum1, m, 64);
            sum2 += __shfl_xor(sum2, m, 64);
            sum3 += __shfl_xor(sum3, m, 64);
        }
        // softmax over the 16 rows (group g holds rows 4g..4g+3, replicated)
        float mx = fmaxf(fmaxf(sum0, sum1), fmaxf(sum2, sum3));
        mx = fmaxf(mx, __shfl_xor(mx, 16, 64));
        mx = fmaxf(mx, __shfl_xor(mx, 32, 64));
        const float ev0 = __expf(sum0 - mx);
        const float ev1 = __expf(sum1 - mx);
        const float ev2 = __expf(sum2 - mx);
        const float ev3 = __expf(sum3 - mx);
        float es = ev0 + ev1 + ev2 + ev3;
        es += __shfl_xor(es, 16, 64);
        es += __shfl_xor(es, 32, 64);
        const float inv = 1.0f / es;

        // ---- A2 fragment: alpha[k], k = half*8 + j  (row-broadcast over l&31)
        // alpha_k lives as ev_{k&3} in group k>>2 (any lane of it).
        u16x8 a2u;
        #pragma unroll
        for (int j = 0; j < 8; ++j) {
            const int src = (((half * 8 + j) >> 2) << 4);   // (k>>2)*16
            float av;
            switch (j & 3) {
                case 0: av = __shfl(ev0, src, 64); break;
                case 1: av = __shfl(ev1, src, 64); break;
                case 2: av = __shfl(ev2, src, 64); break;
                default: av = __shfl(ev3, src, 64); break;
            }
            a2u[j] = f2bf(av * inv);
        }
        const bf16x8 a2 = __builtin_bit_cast(bf16x8, a2u);

        // ---- B2 fragments + agg MFMA (all C rows identical = agg)
        f32x16 z;
        #pragma unroll
        for (int i = 0; i < 16; ++i) z[i] = 0.f;

        float* ao = agg + (size_t)bn * DDIM;
        #pragma unroll
        for (int t = 0; t < 4; ++t) {
            u16x8 bu;
            #pragma unroll
            for (int j = 0; j < 8; ++j) bu[j] = f2bf(b2raw[t][j]);
            const bf16x8 b2 = __builtin_bit_cast(bf16x8, bu);
            const f32x16 r = __builtin_amdgcn_mfma_f32_32x32x16_bf16(a2, b2, z, 0, 0, 0);
            if (lane < 32) ao[t * 32 + col] = r[0];   // row 0 of the 32x32 tile
        }
    }
}

// ---------------- Kernel 2: out = relu([self | agg] @ w3) -------------------
// MFMA GEMM: M=25600 (16 rows/wave), K=256 (8 steps), N=128 (8 tiles).
__global__ __launch_bounds__(256) void k2_out_gemm(
    const float* __restrict__ selfv,  // [BN,128]
    const float* __restrict__ agg,    // [BN,128]
    const float* __restrict__ w3,     // [256,128]
    float* __restrict__ out)          // [BN,128]
{
    __shared__ uint4 w3frag[64][64];  // [t*8+s][lane], 64 KB

    const int tid  = threadIdx.x;
    const int lane = tid & 63;
    const int wave = tid >> 6;
    const int grp  = lane >> 4;
    const int lr   = lane & 15;

    #pragma unroll
    for (int si = 0; si < 2; ++si) {
        const int s = wave + si * 4;
        const int fbase = grp * 8 + 32 * s;
        for (int t = 0; t < 8; ++t) {
            const int d = t * 16 + lr;
            u16x8 tmp;
            #pragma unroll
            for (int j = 0; j < 8; ++j)
                tmp[j] = f2bf(w3[(fbase + j) * DDIM + d]);
            w3frag[t * 8 + s][lane] = __builtin_bit_cast(uint4, tmp);
        }
    }
    __syncthreads();

    const int rowbase = blockIdx.x * 64 + wave * 16;
    const int row = rowbase + lr;

    f32x4 acc[8];
    #pragma unroll
    for (int t = 0; t < 8; ++t) {
        acc[t][0] = 0.f; acc[t][1] = 0.f; acc[t][2] = 0.f; acc[t][3] = 0.f;
    }

    #pragma unroll
    for (int s = 0; s < 8; ++s) {
        const int f0 = grp * 8 + 32 * s;
        const float* srcp = (s < 4) ? (selfv + (size_t)row * DDIM + f0)
                                    : (agg   + (size_t)row * DDIM + (f0 - DDIM));
        const float4 x0 = *(const float4*)srcp;
        const float4 x1 = *(const float4*)(srcp + 4);
        u16x8 au;
        au[0] = f2bf(x0.x); au[1] = f2bf(x0.y); au[2] = f2bf(x0.z); au[3] = f2bf(x0.w);
        au[4] = f2bf(x1.x); au[5] = f2bf(x1.y); au[6] = f2bf(x1.z); au[7] = f2bf(x1.w);
        const bf16x8 af = __builtin_bit_cast(bf16x8, au);
        #pragma unroll
        for (int t = 0; t < 8; ++t) {
            const bf16x8 bf = __builtin_bit_cast(bf16x8, w3frag[t * 8 + s][lane]);
            acc[t] = __builtin_amdgcn_mfma_f32_16x16x32_bf16(af, bf, acc[t], 0, 0, 0);
        }
    }

    #pragma unroll
    for (int t = 0; t < 8; ++t) {
        #pragma unroll
        for (int j = 0; j < 4; ++j) {
            const int r = rowbase + grp * 4 + j;
            out[(size_t)r * DDIM + t * 16 + lr] = fmaxf(acc[t][j], 0.0f);
        }
    }
}

extern "C" void kernel_launch(void* const* d_in, const int* in_sizes, int n_in,
                              void* d_out, int out_size, void* d_ws, size_t ws_size,
                              hipStream_t stream)
{
    const float* selfv = (const float*)d_in[0];
    const float* nbr   = (const float*)d_in[1];
    const float* wgt   = (const float*)d_in[2];
    const float* extra = (const float*)d_in[3];
    const float* w1    = (const float*)d_in[4];
    const float* w2    = (const float*)d_in[5];
    const float* w3    = (const float*)d_in[6];
    float* out = (float*)d_out;
    float* agg = (float*)d_ws;   // BN*128 f32 = 13.1 MB scratch

    hipLaunchKernelGGL(k1_attn_agg, dim3(800), dim3(256), 0, stream,
                       nbr, wgt, extra, w1, w2, agg);
    hipLaunchKernelGGL(k2_out_gemm, dim3(400), dim3(256), 0, stream,
                       selfv, agg, w3, out);
}

// Round 3
// 71.523 us; speedup vs baseline: 1.7908x; 1.7908x over previous
//
#include <hip/hip_runtime.h>
#include <stdint.h>

#define BN_TOTAL 25600   // B*N = 256*100
#define DDIM 128
#define KN 16

typedef __bf16 bf16x8 __attribute__((ext_vector_type(8)));
typedef float f32x4 __attribute__((ext_vector_type(4)));
typedef float f32x16 __attribute__((ext_vector_type(16)));
typedef unsigned short u16x8 __attribute__((ext_vector_type(8)));

__device__ __forceinline__ unsigned short f2bf(float x) {
    unsigned int u = __builtin_bit_cast(unsigned int, x);
    u = (u + 0x7fffu + ((u >> 16) & 1u)) >> 16;   // RNE
    return (unsigned short)u;
}

__device__ __forceinline__ void gload_lds16(const void* g, void* l) {
    __builtin_amdgcn_global_load_lds(
        (const __attribute__((address_space(1))) void*)g,
        (__attribute__((address_space(3))) void*)l, 16, 0, 0);
}

// ---------------- Kernel 0: pre-build w1/w3 bf16 MFMA fragment images --------
// fw1: 32 slots (t*4+s) x 64 lanes of uint4 (bf16x8)  = 32 KB
// fw3: 64 slots (t*8+s) x 64 lanes of uint4 (bf16x8)  = 64 KB
__global__ __launch_bounds__(256) void k0_build_frags(
    const float* __restrict__ w1,   // [129,128]
    const float* __restrict__ w3,   // [256,128]
    uint4* __restrict__ fw1,
    uint4* __restrict__ fw3)
{
    const int slot = blockIdx.x * 256 + threadIdx.x;   // [0, 6144)
    if (slot < 2048) {
        const int idx  = slot >> 6;        // t*4+s
        const int lane = slot & 63;
        const int t = idx >> 2, s = idx & 3;
        const int grp = lane >> 4, lr = lane & 15;
        const int fbase = grp * 8 + 32 * s;
        const int d = t * 16 + lr;
        u16x8 tmp;
        #pragma unroll
        for (int j = 0; j < 8; ++j)
            tmp[j] = f2bf(w1[(fbase + j) * DDIM + d]);
        fw1[slot] = __builtin_bit_cast(uint4, tmp);
    } else {
        const int q = slot - 2048;         // [0, 4096)
        const int idx  = q >> 6;           // t*8+s
        const int lane = q & 63;
        const int t = idx >> 3, s = idx & 7;
        const int grp = lane >> 4, lr = lane & 15;
        const int fbase = grp * 8 + 32 * s;
        const int d = t * 16 + lr;
        u16x8 tmp;
        #pragma unroll
        for (int j = 0; j < 8; ++j)
            tmp[j] = f2bf(w3[(fbase + j) * DDIM + d]);
        fw3[q] = __builtin_bit_cast(uint4, tmp);
    }
}

// ---------------- Kernel 1: attention + aggregation -> agg bf16 [BN][128] ----
// One wave per (b,n), no loop. Grid = 6400 blocks x 4 waves = 25600 waves.
__global__ __launch_bounds__(256) void k1_attn_agg(
    const float* __restrict__ nbr,    // [BN,16,128]
    const float* __restrict__ wgt,    // [BN,16]
    const float* __restrict__ extra,  // [BN,128]
    const float* __restrict__ w1,     // [129,128]
    const float* __restrict__ w2,     // [128]
    const uint4* __restrict__ fw1,    // prebuilt fragments
    unsigned short* __restrict__ aggb)// [BN,128] bf16
{
    __shared__ uint4 b1frag[32][64];   // 32 KB
    __shared__ float w1last[DDIM];
    __shared__ float w2s[DDIM];

    const int tid  = threadIdx.x;
    const int lane = tid & 63;
    const int wave = tid >> 6;
    const int grp  = lane >> 4;   // 0..3
    const int lr   = lane & 15;   // 0..15
    const int half = lane >> 5;   // 0..1  (32x32 MFMA)
    const int col  = lane & 31;   // 0..31 (32x32 MFMA)

    // stage prebuilt w1 fragments: wave w loads slots w*8 .. w*8+7
    #pragma unroll
    for (int c = 0; c < 8; ++c)
        gload_lds16(fw1 + (wave * 8 + c) * 64 + lane, &b1frag[wave * 8 + c][0]);
    if (tid < DDIM) {
        w1last[tid] = w1[DDIM * DDIM + tid];
        w2s[tid]    = w2[tid];
    }
    __syncthreads();

    const int bn = blockIdx.x * 4 + wave;
    const float* nb = nbr   + (size_t)bn * (KN * DDIM);
    const float* ex = extra + (size_t)bn * DDIM;

    // acc init = weight[r] * w1[128][d]   (rows r = grp*4+j, col d = t*16+lr)
    const float4 wv = *(const float4*)(wgt + (size_t)bn * KN + grp * 4);
    f32x4 acc[8];
    #pragma unroll
    for (int t = 0; t < 8; ++t) {
        const float wl = w1last[t * 16 + lr];
        acc[t][0] = wv.x * wl;
        acc[t][1] = wv.y * wl;
        acc[t][2] = wv.z * wl;
        acc[t][3] = wv.w * wl;
    }

    // ---- stage 1: h = feat @ w1  (A-frags from global, B-frags from LDS)
    #pragma unroll
    for (int s = 0; s < 4; ++s) {
        const int f0 = grp * 8 + 32 * s;
        const float4 n0 = *(const float4*)(nb + lr * DDIM + f0);
        const float4 n1 = *(const float4*)(nb + lr * DDIM + f0 + 4);
        const float4 e0 = *(const float4*)(ex + f0);
        const float4 e1 = *(const float4*)(ex + f0 + 4);
        u16x8 au;
        au[0] = f2bf(n0.x * e0.x); au[1] = f2bf(n0.y * e0.y);
        au[2] = f2bf(n0.z * e0.z); au[3] = f2bf(n0.w * e0.w);
        au[4] = f2bf(n1.x * e1.x); au[5] = f2bf(n1.y * e1.y);
        au[6] = f2bf(n1.z * e1.z); au[7] = f2bf(n1.w * e1.w);
        const bf16x8 af = __builtin_bit_cast(bf16x8, au);
        #pragma unroll
        for (int t = 0; t < 8; ++t) {
            const bf16x8 bf = __builtin_bit_cast(bf16x8, b1frag[t * 4 + s][lane]);
            acc[t] = __builtin_amdgcn_mfma_f32_16x16x32_bf16(af, bf, acc[t], 0, 0, 0);
        }
    }

    // ---- issue stage-2 B loads now (L1/L2-hot tile); consumed after softmax.
    // lane needs nbr[k = half*8+j][f = t*32+col]
    float b2raw[4][8];
    #pragma unroll
    for (int t = 0; t < 4; ++t)
        #pragma unroll
        for (int j = 0; j < 8; ++j)
            b2raw[t][j] = nb[(half * 8 + j) * DDIM + t * 32 + col];

    // ---- leaky_relu(0.2) + dot with w2 -> logits for rows grp*4+r
    float sum0 = 0.f, sum1 = 0.f, sum2 = 0.f, sum3 = 0.f;
    #pragma unroll
    for (int t = 0; t < 8; ++t) {
        const float w2v = w2s[t * 16 + lr];
        float h;
        h = acc[t][0]; h = fmaxf(h, 0.2f * h); sum0 = fmaf(h, w2v, sum0);
        h = acc[t][1]; h = fmaxf(h, 0.2f * h); sum1 = fmaf(h, w2v, sum1);
        h = acc[t][2]; h = fmaxf(h, 0.2f * h); sum2 = fmaf(h, w2v, sum2);
        h = acc[t][3]; h = fmaxf(h, 0.2f * h); sum3 = fmaf(h, w2v, sum3);
    }
    #pragma unroll
    for (int m = 1; m <= 8; m <<= 1) {
        sum0 += __shfl_xor(sum0, m, 64);
        sum1 += __shfl_xor(sum1, m, 64);
        sum2 += __shfl_xor(sum2, m, 64);
        sum3 += __shfl_xor(sum3, m, 64);
    }
    // softmax over the 16 rows (group g holds rows 4g..4g+3, replicated)
    float mx = fmaxf(fmaxf(sum0, sum1), fmaxf(sum2, sum3));
    mx = fmaxf(mx, __shfl_xor(mx, 16, 64));
    mx = fmaxf(mx, __shfl_xor(mx, 32, 64));
    const float ev0 = __expf(sum0 - mx);
    const float ev1 = __expf(sum1 - mx);
    const float ev2 = __expf(sum2 - mx);
    const float ev3 = __expf(sum3 - mx);
    float es = ev0 + ev1 + ev2 + ev3;
    es += __shfl_xor(es, 16, 64);
    es += __shfl_xor(es, 32, 64);
    const float inv = 1.0f / es;

    // ---- A2 fragment: alpha[k], k = half*8 + j (row-broadcast over l&31)
    u16x8 a2u;
    #pragma unroll
    for (int j = 0; j < 8; ++j) {
        const int src = (((half * 8 + j) >> 2) << 4);   // (k>>2)*16
        float av;
        switch (j & 3) {
            case 0: av = __shfl(ev0, src, 64); break;
            case 1: av = __shfl(ev1, src, 64); break;
            case 2: av = __shfl(ev2, src, 64); break;
            default: av = __shfl(ev3, src, 64); break;
        }
        a2u[j] = f2bf(av * inv);
    }
    const bf16x8 a2 = __builtin_bit_cast(bf16x8, a2u);

    // ---- agg = alpha^T @ nbr via 4x mfma_32x32x16; all C rows identical.
    f32x16 z;
    #pragma unroll
    for (int i = 0; i < 16; ++i) z[i] = 0.f;

    unsigned short* ao = aggb + (size_t)bn * DDIM;
    #pragma unroll
    for (int t = 0; t < 4; ++t) {
        u16x8 bu;
        #pragma unroll
        for (int j = 0; j < 8; ++j) bu[j] = f2bf(b2raw[t][j]);
        const bf16x8 b2 = __builtin_bit_cast(bf16x8, bu);
        const f32x16 r = __builtin_amdgcn_mfma_f32_32x32x16_bf16(a2, b2, z, 0, 0, 0);
        if (lane < 32) ao[t * 32 + col] = f2bf(r[0]);   // row 0 of the tile
    }
}

// ---------------- Kernel 2: out = relu([self | agg] @ w3) -------------------
// MFMA GEMM: M=25600 (16 rows/wave), K=256 (8 steps), N=128 (8 tiles).
__global__ __launch_bounds__(256) void k2_out_gemm(
    const float* __restrict__ selfv,          // [BN,128] f32
    const unsigned short* __restrict__ aggb,  // [BN,128] bf16
    const uint4* __restrict__ fw3,            // prebuilt fragments
    float* __restrict__ out)                  // [BN,128]
{
    __shared__ uint4 w3frag[64][64];  // 64 KB

    const int tid  = threadIdx.x;
    const int lane = tid & 63;
    const int wave = tid >> 6;
    const int grp  = lane >> 4;
    const int lr   = lane & 15;

    #pragma unroll
    for (int c = 0; c < 16; ++c)
        gload_lds16(fw3 + (wave * 16 + c) * 64 + lane, &w3frag[wave * 16 + c][0]);
    __syncthreads();

    const int rowbase = blockIdx.x * 64 + wave * 16;
    const int row = rowbase + lr;

    f32x4 acc[8];
    #pragma unroll
    for (int t = 0; t < 8; ++t) {
        acc[t][0] = 0.f; acc[t][1] = 0.f; acc[t][2] = 0.f; acc[t][3] = 0.f;
    }

    #pragma unroll
    for (int s = 0; s < 8; ++s) {
        bf16x8 af;
        if (s < 4) {
            const int f0 = grp * 8 + 32 * s;
            const float4 x0 = *(const float4*)(selfv + (size_t)row * DDIM + f0);
            const float4 x1 = *(const float4*)(selfv + (size_t)row * DDIM + f0 + 4);
            u16x8 au;
            au[0] = f2bf(x0.x); au[1] = f2bf(x0.y); au[2] = f2bf(x0.z); au[3] = f2bf(x0.w);
            au[4] = f2bf(x1.x); au[5] = f2bf(x1.y); au[6] = f2bf(x1.z); au[7] = f2bf(x1.w);
            af = __builtin_bit_cast(bf16x8, au);
        } else {
            const int f0 = grp * 8 + 32 * (s - 4);
            const uint4 av = *(const uint4*)(aggb + (size_t)row * DDIM + f0);
            af = __builtin_bit_cast(bf16x8, av);
        }
        #pragma unroll
        for (int t = 0; t < 8; ++t) {
            const bf16x8 bf = __builtin_bit_cast(bf16x8, w3frag[t * 8 + s][lane]);
            acc[t] = __builtin_amdgcn_mfma_f32_16x16x32_bf16(af, bf, acc[t], 0, 0, 0);
        }
    }

    #pragma unroll
    for (int t = 0; t < 8; ++t) {
        #pragma unroll
        for (int j = 0; j < 4; ++j) {
            const int r = rowbase + grp * 4 + j;
            out[(size_t)r * DDIM + t * 16 + lr] = fmaxf(acc[t][j], 0.0f);
        }
    }
}

extern "C" void kernel_launch(void* const* d_in, const int* in_sizes, int n_in,
                              void* d_out, int out_size, void* d_ws, size_t ws_size,
                              hipStream_t stream)
{
    const float* selfv = (const float*)d_in[0];
    const float* nbr   = (const float*)d_in[1];
    const float* wgt   = (const float*)d_in[2];
    const float* extra = (const float*)d_in[3];
    const float* w1    = (const float*)d_in[4];
    const float* w2    = (const float*)d_in[5];
    const float* w3    = (const float*)d_in[6];
    float* out = (float*)d_out;

    // workspace layout: agg bf16 (6.55 MB) | fw1 @ 8 MB (32 KB) | fw3 @ 8 MB+128 KB (64 KB)
    unsigned short* aggb = (unsigned short*)d_ws;
    uint4* fw1 = (uint4*)((char*)d_ws + (8u << 20));
    uint4* fw3 = (uint4*)((char*)d_ws + (8u << 20) + (128u << 10));

    hipLaunchKernelGGL(k0_build_frags, dim3(24), dim3(256), 0, stream, w1, w3, fw1, fw3);
    hipLaunchKernelGGL(k1_attn_agg, dim3(6400), dim3(256), 0, stream,
                       nbr, wgt, extra, w1, w2, fw1, aggb);
    hipLaunchKernelGGL(k2_out_gemm, dim3(400), dim3(256), 0, stream,
                       selfv, aggb, fw3, out);
}